// Round 1
// baseline (659.636 us; speedup 1.0000x reference)
//
#include <hip/hip_runtime.h>
#include <hip/hip_bf16.h>

#define N_NODES 50000
#define E_EDGES 800000
#define D_IN    128
#define HU      256
#define H_HEADS 8
#define U_DIM   32
#define OUT_DIM 64
#define CAP     64

__device__ __forceinline__ float bf2f(unsigned short v) {
    return __uint_as_float(((unsigned)v) << 16);
}

// ---------------- adjacency build (bucket CSR by src) ----------------
__global__ void adj_fill(const int* __restrict__ edges, int* __restrict__ deg,
                         int* __restrict__ adj) {
    int e = blockIdx.x * blockDim.x + threadIdx.x;
    if (e >= E_EDGES) return;
    int2 sd = ((const int2*)edges)[e];
    int slot = atomicAdd(&deg[sd.x], 1);
    if (slot < CAP) adj[(size_t)sd.x * CAP + slot] = sd.y;
}

// ---------------- x0 = relu(ns @ W_pre + b_pre) ----------------
// block: 256 threads (thread = output col), 16 nodes per block
__global__ __launch_bounds__(256) void pre_gemm(const float* __restrict__ ns,
                                                const float* __restrict__ W,
                                                const float* __restrict__ b,
                                                float* __restrict__ x) {
    __shared__ float xs[16][D_IN];
    int t = threadIdx.x;
    int n0 = blockIdx.x * 16;
    const float4* src = (const float4*)(ns + (size_t)n0 * D_IN);
    float4* d4 = (float4*)&xs[0][0];
    d4[t] = src[t];
    d4[t + 256] = src[t + 256];
    __syncthreads();
    float bias = b[t];
    float acc[16];
#pragma unroll
    for (int nb = 0; nb < 16; ++nb) acc[nb] = bias;
    for (int k = 0; k < D_IN; k += 4) {
        float w0 = W[(k + 0) * HU + t];
        float w1 = W[(k + 1) * HU + t];
        float w2 = W[(k + 2) * HU + t];
        float w3 = W[(k + 3) * HU + t];
#pragma unroll
        for (int nb = 0; nb < 16; ++nb) {
            float4 xv = *(const float4*)&xs[nb][k];
            acc[nb] += xv.x * w0 + xv.y * w1 + xv.z * w2 + xv.w * w3;
        }
    }
#pragma unroll
    for (int nb = 0; nb < 16; ++nb) {
        float v = acc[nb];
        x[(size_t)(n0 + nb) * HU + t] = v > 0.f ? v : 0.f;
    }
}

// ---------------- h = x @ W_cat (per layer), h stored bf16 ----------------
// W_att[l] layout: [H][HU][U]; col c = hd*32+u -> W[hd*8192 + k*32 + u]
__global__ __launch_bounds__(256) void h_gemm(const float* __restrict__ x,
                                              const float* __restrict__ Wl,
                                              __hip_bfloat16* __restrict__ h) {
    __shared__ float xs[16][HU];
    int t = threadIdx.x;
    int n0 = blockIdx.x * 16;
    const float4* src = (const float4*)(x + (size_t)n0 * HU);
    float4* d4 = (float4*)&xs[0][0];
#pragma unroll
    for (int i = 0; i < 4; ++i) d4[t + 256 * i] = src[t + 256 * i];
    __syncthreads();
    int hd = t >> 5, u = t & 31;
    const float* Wc = Wl + (size_t)hd * 8192 + u;
    float acc[16];
#pragma unroll
    for (int nb = 0; nb < 16; ++nb) acc[nb] = 0.f;
    for (int k = 0; k < HU; k += 4) {
        float w0 = Wc[(k + 0) * 32];
        float w1 = Wc[(k + 1) * 32];
        float w2 = Wc[(k + 2) * 32];
        float w3 = Wc[(k + 3) * 32];
#pragma unroll
        for (int nb = 0; nb < 16; ++nb) {
            float4 xv = *(const float4*)&xs[nb][k];
            acc[nb] += xv.x * w0 + xv.y * w1 + xv.z * w2 + xv.w * w3;
        }
    }
#pragma unroll
    for (int nb = 0; nb < 16; ++nb) {
        h[(size_t)(n0 + nb) * HU + t] = __float2bfloat16(acc[nb]);
    }
}

// ---------------- s_src/s_dst = per-(node,head) projections of h ----------------
// block: 256 threads = one node; 32-lane group reduce per head
__global__ __launch_bounds__(256) void s_kernel(const __hip_bfloat16* __restrict__ h,
                                                const float* __restrict__ al,
                                                float* __restrict__ ssrc,
                                                float* __restrict__ sdst) {
    int n = blockIdx.x, t = threadIdx.x;
    int hd = t >> 5, u = t & 31;
    float hv = bf2f(((const unsigned short*)h)[(size_t)n * HU + t]);
    float ps = hv * al[hd * 64 + u];
    float pd = hv * al[hd * 64 + 32 + u];
#pragma unroll
    for (int m = 16; m >= 1; m >>= 1) {
        ps += __shfl_xor(ps, m, 64);
        pd += __shfl_xor(pd, m, 64);
    }
    if (u == 0) {
        ssrc[n * H_HEADS + hd] = ps;
        sdst[n * H_HEADS + hd] = pd;
    }
}

// ---------------- fused attention aggregate + relu + residual ----------------
// 1 wave per node: lane t -> head t>>3, cols hd*32+(t&7)*4 .. +3
__global__ __launch_bounds__(64) void agg_kernel(const float* __restrict__ x,
                                                 const __hip_bfloat16* __restrict__ hbf,
                                                 const float* __restrict__ ssrc,
                                                 const float* __restrict__ sdst,
                                                 const int* __restrict__ deg,
                                                 const int* __restrict__ adj,
                                                 float* __restrict__ xo) {
    int n = blockIdx.x, t = threadIdx.x;
    int hd = t >> 3;
    int c = hd * 32 + (t & 7) * 4;
    float ss = ssrc[n * H_HEADS + hd];
    int dg = deg[n];
    dg = dg > CAP ? CAP : dg;
    float a0 = 0.f, a1 = 0.f, a2 = 0.f, a3 = 0.f, den = 0.f;
    const int* arow = adj + (size_t)n * CAP;
    const unsigned short* hb = (const unsigned short*)hbf;
    for (int j = 0; j < dg; ++j) {
        int d = arow[j];
        float sc = ss + sdst[d * H_HEADS + hd];
        sc = sc > 0.f ? sc : 0.2f * sc;              // leaky_relu(0.2)
        sc = fminf(fmaxf(sc, -2.f), 2.f);            // clip
        float w = __expf(sc);
        den += w;
        ushort4 hv = *(const ushort4*)(hb + (size_t)d * HU + c);
        a0 += w * bf2f(hv.x);
        a1 += w * bf2f(hv.y);
        a2 += w * bf2f(hv.z);
        a3 += w * bf2f(hv.w);
    }
    float inv = dg > 0 ? 1.f / den : 0.f;
    float4 xv = *(const float4*)(x + (size_t)n * HU + c);
    float4 o;
    o.x = fmaxf(a0 * inv, 0.f) + xv.x;
    o.y = fmaxf(a1 * inv, 0.f) + xv.y;
    o.z = fmaxf(a2 * inv, 0.f) + xv.z;
    o.w = fmaxf(a3 * inv, 0.f) + xv.w;
    *(float4*)(xo + (size_t)n * HU + c) = o;
}

// ---------------- out = x @ W_out + b_out ----------------
// block: 256 threads, 16 nodes per block; thread = (node-group t>>6, col t&63)
__global__ __launch_bounds__(256) void out_gemm(const float* __restrict__ x,
                                                const float* __restrict__ W,
                                                const float* __restrict__ bo,
                                                float* __restrict__ out) {
    __shared__ float xs[16][HU];
    int t = threadIdx.x;
    int n0 = blockIdx.x * 16;
    const float4* src = (const float4*)(x + (size_t)n0 * HU);
    float4* d4 = (float4*)&xs[0][0];
#pragma unroll
    for (int i = 0; i < 4; ++i) d4[t + 256 * i] = src[t + 256 * i];
    __syncthreads();
    int col = t & 63, ng = t >> 6;
    float bias = bo[col];
    float acc[4] = {bias, bias, bias, bias};
    for (int k = 0; k < HU; k += 4) {
        float w0 = W[(k + 0) * OUT_DIM + col];
        float w1 = W[(k + 1) * OUT_DIM + col];
        float w2 = W[(k + 2) * OUT_DIM + col];
        float w3 = W[(k + 3) * OUT_DIM + col];
#pragma unroll
        for (int i = 0; i < 4; ++i) {
            float4 xv = *(const float4*)&xs[ng * 4 + i][k];
            acc[i] += xv.x * w0 + xv.y * w1 + xv.z * w2 + xv.w * w3;
        }
    }
#pragma unroll
    for (int i = 0; i < 4; ++i)
        out[(size_t)(n0 + ng * 4 + i) * OUT_DIM + col] = acc[i];
}

extern "C" void kernel_launch(void* const* d_in, const int* in_sizes, int n_in,
                              void* d_out, int out_size, void* d_ws, size_t ws_size,
                              hipStream_t stream) {
    const float* ns   = (const float*)d_in[0];
    const int*   edges= (const int*)d_in[1];
    const float* Wpre = (const float*)d_in[2];
    const float* bpre = (const float*)d_in[3];
    const float* Watt = (const float*)d_in[4];
    const float* aatt = (const float*)d_in[5];
    const float* Wout = (const float*)d_in[6];
    const float* bout = (const float*)d_in[7];
    float* out = (float*)d_out;

    char* p = (char*)d_ws;
    float* xA = (float*)p;            p += (size_t)N_NODES * HU * 4;
    float* xB = (float*)p;            p += (size_t)N_NODES * HU * 4;
    __hip_bfloat16* h = (__hip_bfloat16*)p; p += (size_t)N_NODES * HU * 2;
    float* ssrc = (float*)p;          p += (size_t)N_NODES * H_HEADS * 4;
    float* sdst = (float*)p;          p += (size_t)N_NODES * H_HEADS * 4;
    int* deg = (int*)p;               p += (size_t)N_NODES * 4;
    int* adj = (int*)p;               p += (size_t)N_NODES * CAP * 4;

    hipMemsetAsync(deg, 0, (size_t)N_NODES * 4, stream);
    adj_fill<<<(E_EDGES + 255) / 256, 256, 0, stream>>>(edges, deg, adj);

    pre_gemm<<<N_NODES / 16, 256, 0, stream>>>(ns, Wpre, bpre, xA);

    float* xc = xA;
    float* xn = xB;
    for (int l = 0; l < 2; ++l) {
        h_gemm<<<N_NODES / 16, 256, 0, stream>>>(xc, Watt + (size_t)l * 65536, h);
        s_kernel<<<N_NODES, 256, 0, stream>>>(h, aatt + (size_t)l * 512, ssrc, sdst);
        agg_kernel<<<N_NODES, 64, 0, stream>>>(xc, h, ssrc, sdst, deg, adj, xn);
        float* tmp = xc; xc = xn; xn = tmp;
    }

    out_gemm<<<N_NODES / 16, 256, 0, stream>>>(xc, Wout, bout, out);
}

// Round 2
// 355.533 us; speedup vs baseline: 1.8553x; 1.8553x over previous
//
#include <hip/hip_runtime.h>
#include <hip/hip_bf16.h>

#define N_NODES 50000
#define E_EDGES 800000
#define D_IN    128
#define HU      256
#define H_HEADS 8
#define U_DIM   32
#define OUT_DIM 64
#define CAP     64

typedef __attribute__((ext_vector_type(8))) short short8v;
typedef __attribute__((ext_vector_type(4))) float f32x4;

__device__ __forceinline__ float bf2f(unsigned short v) {
    return __uint_as_float(((unsigned)v) << 16);
}
__device__ __forceinline__ unsigned short f2b(float f) {  // RNE f32->bf16
    unsigned u = __float_as_uint(f);
    return (unsigned short)((u + 0x7FFFu + ((u >> 16) & 1u)) >> 16);
}

// ---------------- adjacency build (bucket CSR by src) ----------------
__global__ void adj_fill(const int* __restrict__ edges, int* __restrict__ deg,
                         int* __restrict__ adj) {
    int e = blockIdx.x * blockDim.x + threadIdx.x;
    if (e >= E_EDGES) return;
    int2 sd = ((const int2*)edges)[e];
    int slot = atomicAdd(&deg[sd.x], 1);
    if (slot < CAP) adj[(size_t)sd.x * CAP + slot] = sd.y;
}

// ---------------- W -> MFMA B-fragment order (bf16) ----------------
// frag layout: Wf[(((ct*(K/32)+ks)*64 + lane)*8 + j] = W[k][n],
//   k = ks*32 + (lane>>4)*8 + j,  n = ct*16 + (lane&15)
// GAT=true: W is [H][K][32] (heads), col n -> head n>>5, u n&31
template<int K, int N, bool GAT>
__global__ __launch_bounds__(256) void wfrag_kernel(const float* __restrict__ W,
                                                    unsigned short* __restrict__ Wf) {
    int tid = blockIdx.x * 256 + threadIdx.x;
    if (tid >= K * N) return;
    int j  = tid & 7;
    int l  = (tid >> 3) & 63;
    int fb = tid >> 9;
    int ks = fb % (K / 32);
    int ct = fb / (K / 32);
    int k  = ks * 32 + (l >> 4) * 8 + j;
    int n  = ct * 16 + (l & 15);
    float v = GAT ? W[(size_t)(n >> 5) * (K * 32) + k * 32 + (n & 31)]
                  : W[(size_t)k * N + n];
    Wf[tid] = f2b(v);
}

// ---------------- MFMA GEMM: C[64 x N] = A[64 x K] * W[K x N] ----------------
// MODE 0: f32 out, +bias, relu (pre)   MODE 1: bf16 out (h)   MODE 2: f32 out, +bias (out)
template<int K, int N, int MT, int NT, int MODE>
__global__ __launch_bounds__(256) void mfma_gemm(const float* __restrict__ A,
                                                 const unsigned short* __restrict__ Wf,
                                                 const float* __restrict__ bias,
                                                 void* __restrict__ Cout) {
    constexpr int SK = K + 8;                 // pad: frag reads -> 2-way (free)
    __shared__ __align__(16) unsigned short as[64 * SK];
    int t  = threadIdx.x;
    int n0 = blockIdx.x * 64;

    // stage A tile fp32 -> bf16 LDS
    constexpr int K4 = K / 4;
    const float4* A4 = (const float4*)A;
    for (int i = t; i < 64 * K4; i += 256) {
        int row = i / K4, c4 = i % K4;
        float4 v = make_float4(0.f, 0.f, 0.f, 0.f);
        if (n0 + row < N_NODES) v = A4[(size_t)(n0 + row) * K4 + c4];
        ushort4 pk;
        pk.x = f2b(v.x); pk.y = f2b(v.y); pk.z = f2b(v.z); pk.w = f2b(v.w);
        *(ushort4*)&as[row * SK + c4 * 4] = pk;
    }
    __syncthreads();

    int wid = t >> 6, l = t & 63;
    constexpr int NWN = N / (NT * 16);        // waves along N
    int col0 = (wid % NWN) * (NT * 16);
    int row0 = (wid / NWN) * (MT * 16);

    f32x4 acc[MT][NT];
#pragma unroll
    for (int mt = 0; mt < MT; ++mt)
#pragma unroll
        for (int nt = 0; nt < NT; ++nt)
            acc[mt][nt] = (f32x4){0.f, 0.f, 0.f, 0.f};

    int ar  = l & 15;
    int akb = (l >> 4) * 8;
#pragma unroll
    for (int ks = 0; ks < K / 32; ++ks) {
        short8v a[MT], b[NT];
#pragma unroll
        for (int mt = 0; mt < MT; ++mt)
            a[mt] = *(const short8v*)&as[(row0 + mt * 16 + ar) * SK + ks * 32 + akb];
#pragma unroll
        for (int nt = 0; nt < NT; ++nt)
            b[nt] = *(const short8v*)&Wf[(size_t)(((((col0 >> 4) + nt) * (K / 32)) + ks) * 64 + l) * 8];
#pragma unroll
        for (int mt = 0; mt < MT; ++mt)
#pragma unroll
            for (int nt = 0; nt < NT; ++nt)
                acc[mt][nt] = __builtin_amdgcn_mfma_f32_16x16x32_bf16(a[mt], b[nt], acc[mt][nt], 0, 0, 0);
    }

    // epilogue: C/D layout col=lane&15, row=(lane>>4)*4+reg  [m89]
    int crow = (l >> 4) * 4, ccol = l & 15;
#pragma unroll
    for (int mt = 0; mt < MT; ++mt) {
#pragma unroll
        for (int nt = 0; nt < NT; ++nt) {
            int gc = col0 + nt * 16 + ccol;
#pragma unroll
            for (int r = 0; r < 4; ++r) {
                int gr = n0 + row0 + mt * 16 + crow + r;
                if (gr >= N_NODES) continue;
                float v = acc[mt][nt][r];
                if (MODE == 0) {
                    v += bias[gc];
                    ((float*)Cout)[(size_t)gr * N + gc] = fmaxf(v, 0.f);
                } else if (MODE == 1) {
                    ((unsigned short*)Cout)[(size_t)gr * N + gc] = f2b(v);
                } else {
                    ((float*)Cout)[(size_t)gr * N + gc] = v + bias[gc];
                }
            }
        }
    }
}

// ---------------- s_src/s_dst = per-(node,head) projections of h ----------------
__global__ __launch_bounds__(256) void s_kernel(const unsigned short* __restrict__ h,
                                                const float* __restrict__ al,
                                                float* __restrict__ ssrc,
                                                float* __restrict__ sdst) {
    int n = blockIdx.x, t = threadIdx.x;
    int hd = t >> 5, u = t & 31;
    float hv = bf2f(h[(size_t)n * HU + t]);
    float ps = hv * al[hd * 64 + u];
    float pd = hv * al[hd * 64 + 32 + u];
#pragma unroll
    for (int m = 16; m >= 1; m >>= 1) {
        ps += __shfl_xor(ps, m, 64);
        pd += __shfl_xor(pd, m, 64);
    }
    if (u == 0) {
        ssrc[n * H_HEADS + hd] = ps;
        sdst[n * H_HEADS + hd] = pd;
    }
}

// ---------------- fused attention aggregate + relu + residual (in-place x) ----------------
__global__ __launch_bounds__(64) void agg_kernel(const float* __restrict__ x,
                                                 const unsigned short* __restrict__ hb,
                                                 const float* __restrict__ ssrc,
                                                 const float* __restrict__ sdst,
                                                 const int* __restrict__ deg,
                                                 const int* __restrict__ adj,
                                                 float* __restrict__ xo) {
    int n = blockIdx.x, t = threadIdx.x;
    int hd = t >> 3;
    int c = hd * 32 + (t & 7) * 4;
    float ss = ssrc[n * H_HEADS + hd];
    int dg = deg[n];
    dg = dg > CAP ? CAP : dg;
    float a0 = 0.f, a1 = 0.f, a2 = 0.f, a3 = 0.f, den = 0.f;
    const int* arow = adj + (size_t)n * CAP;
    for (int j = 0; j < dg; ++j) {
        int d = arow[j];
        float sc = ss + sdst[d * H_HEADS + hd];
        sc = sc > 0.f ? sc : 0.2f * sc;              // leaky_relu(0.2)
        sc = fminf(fmaxf(sc, -2.f), 2.f);            // clip
        float w = __expf(sc);
        den += w;
        ushort4 hv = *(const ushort4*)(hb + (size_t)d * HU + c);
        a0 += w * bf2f(hv.x);
        a1 += w * bf2f(hv.y);
        a2 += w * bf2f(hv.z);
        a3 += w * bf2f(hv.w);
    }
    float inv = dg > 0 ? 1.f / den : 0.f;
    float4 xv = *(const float4*)(x + (size_t)n * HU + c);
    float4 o;
    o.x = fmaxf(a0 * inv, 0.f) + xv.x;
    o.y = fmaxf(a1 * inv, 0.f) + xv.y;
    o.z = fmaxf(a2 * inv, 0.f) + xv.z;
    o.w = fmaxf(a3 * inv, 0.f) + xv.w;
    *(float4*)(xo + (size_t)n * HU + c) = o;
}

extern "C" void kernel_launch(void* const* d_in, const int* in_sizes, int n_in,
                              void* d_out, int out_size, void* d_ws, size_t ws_size,
                              hipStream_t stream) {
    const float* ns   = (const float*)d_in[0];
    const int*   edges= (const int*)d_in[1];
    const float* Wpre = (const float*)d_in[2];
    const float* bpre = (const float*)d_in[3];
    const float* Watt = (const float*)d_in[4];
    const float* aatt = (const float*)d_in[5];
    const float* Wout = (const float*)d_in[6];
    const float* bout = (const float*)d_in[7];
    float* out = (float*)d_out;

    char* p = (char*)d_ws;
    float* xA = (float*)p;                    p += (size_t)N_NODES * HU * 4;
    unsigned short* h = (unsigned short*)p;   p += (size_t)N_NODES * HU * 2;
    float* ssrc = (float*)p;                  p += (size_t)N_NODES * H_HEADS * 4;
    float* sdst = (float*)p;                  p += (size_t)N_NODES * H_HEADS * 4;
    int* deg = (int*)p;                       p += (size_t)N_NODES * 4;
    int* adj = (int*)p;                       p += (size_t)N_NODES * CAP * 4;
    unsigned short* wf_pre  = (unsigned short*)p; p += (size_t)D_IN * HU * 2;
    unsigned short* wf_att0 = (unsigned short*)p; p += (size_t)HU * HU * 2;
    unsigned short* wf_att1 = (unsigned short*)p; p += (size_t)HU * HU * 2;
    unsigned short* wf_out  = (unsigned short*)p; p += (size_t)HU * OUT_DIM * 2;

    // weight repacks (cheap, run every launch)
    wfrag_kernel<D_IN, HU, false><<<(D_IN * HU) / 256, 256, 0, stream>>>(Wpre, wf_pre);
    wfrag_kernel<HU, HU, true><<<(HU * HU) / 256, 256, 0, stream>>>(Watt, wf_att0);
    wfrag_kernel<HU, HU, true><<<(HU * HU) / 256, 256, 0, stream>>>(Watt + 65536, wf_att1);
    wfrag_kernel<HU, OUT_DIM, false><<<(HU * OUT_DIM) / 256, 256, 0, stream>>>(Wout, wf_out);

    hipMemsetAsync(deg, 0, (size_t)N_NODES * 4, stream);
    adj_fill<<<(E_EDGES + 255) / 256, 256, 0, stream>>>(edges, deg, adj);

    const int GB = (N_NODES + 63) / 64;   // 782
    mfma_gemm<D_IN, HU, 4, 4, 0><<<GB, 256, 0, stream>>>(ns, wf_pre, bpre, xA);

    unsigned short* wf_att[2] = {wf_att0, wf_att1};
    for (int l = 0; l < 2; ++l) {
        mfma_gemm<HU, HU, 4, 4, 1><<<GB, 256, 0, stream>>>(xA, wf_att[l], nullptr, h);
        s_kernel<<<N_NODES, 256, 0, stream>>>(h, aatt + (size_t)l * 512, ssrc, sdst);
        agg_kernel<<<N_NODES, 64, 0, stream>>>(xA, h, ssrc, sdst, deg, adj, xA);
    }

    mfma_gemm<HU, OUT_DIM, 1, 4, 2><<<GB, 256, 0, stream>>>(xA, wf_out, bout, out);
}